// Round 3
// baseline (490.304 us; speedup 1.0000x reference)
//
#include <hip/hip_runtime.h>
#include <math.h>

#define NN 50000
#define EE 800000
#define IN_C 128
#define HID 64
#define HEADS 4
#define EEP 950000                       // padded CSR capacity: EE + 3*NN (rows padded to %4)
#define SCAN_BLOCKS ((NN + 255) / 256)   // 196
#define EBLOCKS ((EE + 255) / 256)       // 3125

typedef __attribute__((ext_vector_type(8))) short bf16x8;
typedef __attribute__((ext_vector_type(4))) float f32x4;

#if defined(__has_builtin)
#if __has_builtin(__builtin_amdgcn_fdot2_f32_bf16)
#define HAVE_FDOT2_BF16 1
#endif
#endif

// ---------------- helpers ----------------

__device__ inline unsigned short f2bf(float f) {       // fp32 -> bf16 RNE
    unsigned u = __float_as_uint(f);
    return (unsigned short)((u + 0x7fff + ((u >> 16) & 1)) >> 16);
}
__device__ inline float bf2f(unsigned short s) {
    return __uint_as_float(((unsigned)s) << 16);
}
__device__ inline unsigned prm(unsigned a, unsigned b, unsigned sel) {
    return __builtin_amdgcn_perm(a, b, sel);
}
#ifdef HAVE_FDOT2_BF16
typedef __attribute__((ext_vector_type(2))) __bf16 bf2v;
__device__ inline float fdot2bf(unsigned h, unsigned w, float acc) {
    return __builtin_amdgcn_fdot2_f32_bf16(__builtin_bit_cast(bf2v, h),
                                           __builtin_bit_cast(bf2v, w), acc, false);
}
#else
__device__ inline float fdot2bf(unsigned h, unsigned w, float acc) {
    return acc + bf2f((unsigned short)(h & 0xffff)) * bf2f((unsigned short)(w & 0xffff))
               + bf2f((unsigned short)(h >> 16)) * bf2f((unsigned short)(w >> 16));
}
#endif

__device__ inline int wave_incl_scan(int v, int lane) {
    #pragma unroll
    for (int off = 1; off < 64; off <<= 1) {
        int t = __shfl_up(v, off);
        if (lane >= off) v += t;
    }
    return v;
}

__device__ inline int block256_excl_scan(int v, int tid, int* ws4) {
    int lane = tid & 63, wv = tid >> 6;
    int incl = wave_incl_scan(v, lane);
    if (lane == 63) ws4[wv] = incl;
    __syncthreads();
    if (tid == 0) {
        int run = 0;
        #pragma unroll
        for (int i = 0; i < 4; i++) { int t = ws4[i]; ws4[i] = run; run += t; }
    }
    __syncthreads();
    return incl + ws4[wv] - v;
}

// ---------------- front: degree histogram (+edge ranks) + weight splits ----------------

__global__ void front_kernel(const int* __restrict__ ei, int* __restrict__ deg,
                             unsigned short* __restrict__ rank,
                             const float* __restrict__ W1, unsigned short* __restrict__ W1Thi,
                             unsigned short* __restrict__ W1Tlo,
                             const float* __restrict__ W2, unsigned short* __restrict__ W2Thi,
                             unsigned short* __restrict__ W2Tlo) {
    int b = blockIdx.x;
    int tid = threadIdx.x;
    if (b < EBLOCKS) {
        int i = b * 256 + tid;
        if (i < EE) rank[i] = (unsigned short)atomicAdd(&deg[ei[EE + i]], 1);
    } else if (b < EBLOCKS + 128) {
        int idx = (b - EBLOCKS) * 256 + tid;         // W1 [128][256]
        int r = idx >> 8, c = idx & 255;
        float v = W1[idx];
        unsigned short h = f2bf(v);
        W1Thi[c * 128 + r] = h;
        W1Tlo[c * 128 + r] = f2bf(v - bf2f(h));
    } else {
        int idx = (b - EBLOCKS - 128) * 256 + tid;   // W2 [256][64]
        int r = idx >> 6, c = idx & 63;
        float v = W2[idx];
        unsigned short h = f2bf(v);
        W2Thi[c * 256 + r] = h;
        W2Tlo[c * 256 + r] = f2bf(v - bf2f(h));
    }
}

// ---------------- single-pass CSR scan (decoupled lookback), rows padded to %4 ----------
// Also zeroes the pad slots of csr_src / w1t / w2t so the agg loops need no tail masking.
__global__ void scan_fill_kernel(const int* __restrict__ deg,
                                 unsigned long long* __restrict__ desc,
                                 int* __restrict__ row_ptr,
                                 unsigned short* __restrict__ csr_src,
                                 unsigned short* __restrict__ w1t,
                                 unsigned short* __restrict__ w2t) {
    __shared__ int ws4[4];
    __shared__ int sbase;
    int b = blockIdx.x, tid = threadIdx.x;
    int idx = b * 256 + tid;
    int draw = (idx < NN) ? deg[idx] : 0;
    int d = (draw + 3) & ~3;                 // pad each row to multiple of 4
    int excl = block256_excl_scan(d, tid, ws4);
    if (tid == 255) {
        unsigned total = (unsigned)(excl + d);
        __threadfence();
        atomicExch(&desc[b], (1ULL << 32) | (unsigned long long)total);
    }
    if (tid < 64) {
        int sum = 0;
        int hi = b;
        while (hi > 0) {
            int lo = hi - 64; if (lo < 0) lo = 0;
            int myi = lo + tid;
            unsigned v = 0;
            if (myi < hi) {
                unsigned long long d8;
                do { d8 = atomicAdd(&desc[myi], 0ULL); } while ((d8 >> 32) == 0);
                v = (unsigned)(d8 & 0xffffffffULL);
            }
            #pragma unroll
            for (int off = 32; off; off >>= 1) v += __shfl_down(v, off);
            v = __shfl(v, 0);
            sum += (int)v;
            hi = lo;
        }
        if (tid == 0) sbase = sum;
    }
    __syncthreads();
    int gbase = sbase;
    if (idx < NN) {
        int rp = gbase + excl;
        row_ptr[idx] = rp;
        // zero the 0-3 pad slots (weight 0 => zero contribution in agg)
        for (int p = rp + draw; p < rp + d; ++p) {
            csr_src[p] = 0;
            w2t[p] = 0;
            w1t[p] = 0; w1t[EEP + p] = 0; w1t[2 * EEP + p] = 0; w1t[3 * EEP + p] = 0;
        }
    }
    if (b == gridDim.x - 1 && tid == 255) row_ptr[NN] = gbase + excl + d;
}

// ---------------- layer-1 MFMA GEMM + fused alpha ----------------
__global__ __launch_bounds__(256) void gemm1_mfma(
        const float* __restrict__ x,
        const unsigned short* __restrict__ Bhi, const unsigned short* __restrict__ Blo,
        const float* __restrict__ a_src, const float* __restrict__ a_dst,
        unsigned short* __restrict__ h1b, float* __restrict__ as1, float* __restrict__ ad1) {
    __shared__ unsigned short Ahi[64][136];   // +8 pad
    __shared__ unsigned short Alo[64][136];
    int tid = threadIdx.x;
    int w = tid >> 6, lane = tid & 63;
    int lq = lane >> 4, lr = lane & 15;
    int brow = blockIdx.x * 64;
    {
        int row = tid >> 2;                    // 0..63
        int col0 = (tid & 3) * 32;             // 0,32,64,96
        int gr = min(brow + row, NN - 1);
        #pragma unroll
        for (int i = 0; i < 32; i += 4) {
            float4 v = *(const float4*)(x + (size_t)gr * 128 + col0 + i);
            unsigned short h0 = f2bf(v.x), h1 = f2bf(v.y), h2 = f2bf(v.z), h3 = f2bf(v.w);
            Ahi[row][col0 + i + 0] = h0; Alo[row][col0 + i + 0] = f2bf(v.x - bf2f(h0));
            Ahi[row][col0 + i + 1] = h1; Alo[row][col0 + i + 1] = f2bf(v.y - bf2f(h1));
            Ahi[row][col0 + i + 2] = h2; Alo[row][col0 + i + 2] = f2bf(v.z - bf2f(h2));
            Ahi[row][col0 + i + 3] = h3; Alo[row][col0 + i + 3] = f2bf(v.w - bf2f(h3));
        }
    }
    __syncthreads();
    f32x4 acc[4][4];
    f32x4 zf = {0.f, 0.f, 0.f, 0.f};
    #pragma unroll
    for (int mi = 0; mi < 4; mi++)
        #pragma unroll
        for (int ni = 0; ni < 4; ni++) acc[mi][ni] = zf;
    #pragma unroll
    for (int q = 0; q < 4; q++) {
        int ko = q * 32 + lq * 8;
        bf16x8 ah[4], al[4];
        #pragma unroll
        for (int mi = 0; mi < 4; mi++) {
            ah[mi] = *(const bf16x8*)(const void*)&Ahi[mi * 16 + lr][ko];
            al[mi] = *(const bf16x8*)(const void*)&Alo[mi * 16 + lr][ko];
        }
        #pragma unroll
        for (int ni = 0; ni < 4; ni++) {
            size_t bo = (size_t)(w * 64 + ni * 16 + lr) * 128 + ko;
            bf16x8 bh = *(const bf16x8*)(const void*)(Bhi + bo);
            bf16x8 bl = *(const bf16x8*)(const void*)(Blo + bo);
            #pragma unroll
            for (int mi = 0; mi < 4; mi++) {
                acc[mi][ni] = __builtin_amdgcn_mfma_f32_16x16x32_bf16(al[mi], bh, acc[mi][ni], 0, 0, 0);
                acc[mi][ni] = __builtin_amdgcn_mfma_f32_16x16x32_bf16(ah[mi], bl, acc[mi][ni], 0, 0, 0);
                acc[mi][ni] = __builtin_amdgcn_mfma_f32_16x16x32_bf16(ah[mi], bh, acc[mi][ni], 0, 0, 0);
            }
        }
    }
    float asv[4], adv[4];
    #pragma unroll
    for (int ni = 0; ni < 4; ni++) {
        asv[ni] = a_src[w * 64 + ni * 16 + lr];
        adv[ni] = a_dst[w * 64 + ni * 16 + lr];
    }
    #pragma unroll
    for (int mi = 0; mi < 4; mi++) {
        f32x4 ps = zf, pd = zf;
        #pragma unroll
        for (int ni = 0; ni < 4; ni++)
            #pragma unroll
            for (int r = 0; r < 4; r++) {
                ps[r] += acc[mi][ni][r] * asv[ni];
                pd[r] += acc[mi][ni][r] * adv[ni];
            }
        #pragma unroll
        for (int m = 1; m < 16; m <<= 1)
            #pragma unroll
            for (int r = 0; r < 4; r++) {
                ps[r] += __shfl_xor(ps[r], m);
                pd[r] += __shfl_xor(pd[r], m);
            }
        #pragma unroll
        for (int r = 0; r < 4; r++) {
            int n = brow + mi * 16 + lq * 4 + r;
            if (lr == 0 && n < NN) { as1[n * 4 + w] = ps[r]; ad1[n * 4 + w] = pd[r]; }
        }
        #pragma unroll
        for (int ni = 0; ni < 4; ni++)
            #pragma unroll
            for (int r = 0; r < 4; r++) {
                int n = brow + mi * 16 + lq * 4 + r;
                if (n < NN)
                    h1b[(size_t)n * 256 + w * 64 + ni * 16 + lr] = f2bf(acc[mi][ni][r]);
            }
    }
}

// ---------------- layer-2 MFMA GEMM + fused alpha (single-bf16 A) ----------------
__global__ __launch_bounds__(256) void gemm2_mfma(
        const unsigned short* __restrict__ Ab,
        const unsigned short* __restrict__ Bhi, const unsigned short* __restrict__ Blo,
        const float* __restrict__ a_src, const float* __restrict__ a_dst,
        unsigned short* __restrict__ g2b, float* __restrict__ as2, float* __restrict__ ad2) {
    int tid = threadIdx.x;
    int w = tid >> 6, lane = tid & 63;
    int lq = lane >> 4, lr = lane & 15;
    int wrow = blockIdx.x * 128 + w * 32;
    f32x4 acc[2][4];
    f32x4 zf = {0.f, 0.f, 0.f, 0.f};
    #pragma unroll
    for (int mi = 0; mi < 2; mi++)
        #pragma unroll
        for (int ni = 0; ni < 4; ni++) acc[mi][ni] = zf;
    int ra = min(wrow + lr, NN - 1);
    int rb = min(wrow + 16 + lr, NN - 1);
    #pragma unroll
    for (int q = 0; q < 8; q++) {
        int ko = q * 32 + lq * 8;
        bf16x8 ah0 = *(const bf16x8*)(const void*)(Ab + (size_t)ra * 256 + ko);
        bf16x8 ah1 = *(const bf16x8*)(const void*)(Ab + (size_t)rb * 256 + ko);
        #pragma unroll
        for (int ni = 0; ni < 4; ni++) {
            size_t bo = (size_t)(ni * 16 + lr) * 256 + ko;
            bf16x8 bh = *(const bf16x8*)(const void*)(Bhi + bo);
            bf16x8 bl = *(const bf16x8*)(const void*)(Blo + bo);
            acc[0][ni] = __builtin_amdgcn_mfma_f32_16x16x32_bf16(ah0, bl, acc[0][ni], 0, 0, 0);
            acc[0][ni] = __builtin_amdgcn_mfma_f32_16x16x32_bf16(ah0, bh, acc[0][ni], 0, 0, 0);
            acc[1][ni] = __builtin_amdgcn_mfma_f32_16x16x32_bf16(ah1, bl, acc[1][ni], 0, 0, 0);
            acc[1][ni] = __builtin_amdgcn_mfma_f32_16x16x32_bf16(ah1, bh, acc[1][ni], 0, 0, 0);
        }
    }
    float asv[4], adv[4];
    #pragma unroll
    for (int ni = 0; ni < 4; ni++) {
        asv[ni] = a_src[ni * 16 + lr];
        adv[ni] = a_dst[ni * 16 + lr];
    }
    #pragma unroll
    for (int mi = 0; mi < 2; mi++) {
        f32x4 ps = zf, pd = zf;
        #pragma unroll
        for (int ni = 0; ni < 4; ni++)
            #pragma unroll
            for (int r = 0; r < 4; r++) {
                ps[r] += acc[mi][ni][r] * asv[ni];
                pd[r] += acc[mi][ni][r] * adv[ni];
            }
        #pragma unroll
        for (int m = 1; m < 16; m <<= 1)
            #pragma unroll
            for (int r = 0; r < 4; r++) {
                ps[r] += __shfl_xor(ps[r], m);
                pd[r] += __shfl_xor(pd[r], m);
            }
        #pragma unroll
        for (int r = 0; r < 4; r++) {
            int n = wrow + mi * 16 + lq * 4 + r;
            if (lr == 0 && n < NN) { as2[n] = ps[r]; ad2[n] = pd[r]; }
        }
        #pragma unroll
        for (int ni = 0; ni < 4; ni++)
            #pragma unroll
            for (int r = 0; r < 4; r++) {
                int n = wrow + mi * 16 + lq * 4 + r;
                if (n < NN)
                    g2b[(size_t)n * 64 + ni * 16 + lr] = f2bf(acc[mi][ni][r]);
            }
    }
}

// ---------------- scatter + layer-1 edge weights (full-lane, edge-parallel) -------------
__global__ __launch_bounds__(256) void scatter_w1_kernel(
        const int* __restrict__ ei, const unsigned short* __restrict__ rank,
        const int* __restrict__ row_ptr, const float* __restrict__ as1,
        const float* __restrict__ ad1, unsigned short* __restrict__ csr_src,
        unsigned short* __restrict__ w1t, float* __restrict__ den1) {
    int i = blockIdx.x * 256 + threadIdx.x;
    if (i >= EE) return;
    int s = ei[i], d = ei[EE + i];
    int pos = row_ptr[d] + (int)rank[i];
    csr_src[pos] = (unsigned short)s;
    float4 av = ((const float4*)as1)[s];
    float4 bv = ((const float4*)ad1)[d];
    float e0 = av.x + bv.x; e0 = e0 > 0.f ? e0 : 0.2f * e0; float x0 = __expf(e0);
    float e1 = av.y + bv.y; e1 = e1 > 0.f ? e1 : 0.2f * e1; float x1 = __expf(e1);
    float e2 = av.z + bv.z; e2 = e2 > 0.f ? e2 : 0.2f * e2; float x2 = __expf(e2);
    float e3 = av.w + bv.w; e3 = e3 > 0.f ? e3 : 0.2f * e3; float x3 = __expf(e3);
    w1t[pos]           = f2bf(x0);
    w1t[EEP + pos]     = f2bf(x1);
    w1t[2 * EEP + pos] = f2bf(x2);
    w1t[3 * EEP + pos] = f2bf(x3);
    atomicAdd(den1 + d * 4 + 0, x0);
    atomicAdd(den1 + d * 4 + 1, x1);
    atomicAdd(den1 + d * 4 + 2, x2);
    atomicAdd(den1 + d * 4 + 3, x3);
}

// ---------------- layer-2 edge weights ----------------
__global__ __launch_bounds__(256) void w2_kernel(
        const int* __restrict__ ei, const unsigned short* __restrict__ rank,
        const int* __restrict__ row_ptr, const float* __restrict__ as2,
        const float* __restrict__ ad2, unsigned short* __restrict__ w2t,
        float* __restrict__ den2) {
    int i = blockIdx.x * 256 + threadIdx.x;
    if (i >= EE) return;
    int s = ei[i], d = ei[EE + i];
    int pos = row_ptr[d] + (int)rank[i];
    float e = as2[s] + ad2[d];
    e = e > 0.f ? e : 0.2f * e;
    float x = __expf(e);
    w2t[pos] = f2bf(x);
    atomicAdd(den2 + d, x);
}

// ---------------- layer-1 aggregation: half-wave paired gather, 2-deep pipeline --------
// Source-id staging uses a dword LDS array (uint store / uint load) so the dependence is
// type-visible to the compiler -- the r1 ushort-store/uint-load pun let TBAA reorder the
// pair-decode above the staging store (wrong gathers -> absmax 0.71).
__global__ __launch_bounds__(256, 4) void agg1_kernel(
        const unsigned short* __restrict__ h1b, const int* __restrict__ row_ptr,
        const unsigned short* __restrict__ csr_src, const unsigned short* __restrict__ w1t,
        const float* __restrict__ den1, const float* __restrict__ b1,
        unsigned short* __restrict__ h2b) {
    __shared__ unsigned ssrc32[4][32];
    int tid = threadIdx.x;
    int wv = tid >> 6, lane = tid & 63;
    int n = blockIdx.x * 4 + wv;
    if (n >= NN) return;
    int start = row_ptr[n], end = row_ptr[n + 1];
    int H = lane >> 5, l5 = lane & 31;
    int h = l5 >> 3;                               // head of this lane's 8 channels
    const unsigned short* __restrict__ wr = w1t + (size_t)h * EEP;
    const unsigned short* __restrict__ hp = h1b + l5 * 8;
    f32x4 a0 = {0.f, 0.f, 0.f, 0.f}, a1 = {0.f, 0.f, 0.f, 0.f};
    uint4 LA0, LB0, LA1, LB1;
    unsigned wp0, wp1;
    for (int c0 = start; c0 < end; c0 += 64) {
        int m = min(64, end - c0);                 // multiple of 4 (padded rows)
        if (lane < (m >> 1))                       // stage packed src-id pairs as dwords
            ssrc32[wv][lane] = *(const unsigned*)(const void*)(csr_src + c0 + 2 * lane);
        int G = m >> 2;
        auto LD = [&](int g, uint4& A, uint4& B, unsigned& wp) {
            unsigned both = ssrc32[wv][2 * g + H];
            int ia = (int)(both & 0xffffu), ib = (int)(both >> 16);
            A = *(const uint4*)(const void*)(hp + ia * 256);
            B = *(const uint4*)(const void*)(hp + ib * 256);
            wp = *(const unsigned*)(const void*)(wr + c0 + 4 * g + 2 * H);
        };
        auto CMP = [&](const uint4& A, const uint4& B, unsigned wp) {
            a0.x = fdot2bf(prm(B.x, A.x, 0x05040100), wp, a0.x);
            a0.y = fdot2bf(prm(B.x, A.x, 0x07060302), wp, a0.y);
            a0.z = fdot2bf(prm(B.y, A.y, 0x05040100), wp, a0.z);
            a0.w = fdot2bf(prm(B.y, A.y, 0x07060302), wp, a0.w);
            a1.x = fdot2bf(prm(B.z, A.z, 0x05040100), wp, a1.x);
            a1.y = fdot2bf(prm(B.z, A.z, 0x07060302), wp, a1.y);
            a1.z = fdot2bf(prm(B.w, A.w, 0x05040100), wp, a1.z);
            a1.w = fdot2bf(prm(B.w, A.w, 0x07060302), wp, a1.w);
        };
        LD(0, LA0, LB0, wp0);
        if (G > 1) LD(1, LA1, LB1, wp1);
        int g = 0;
        while (true) {
            CMP(LA0, LB0, wp0);
            if (g + 2 < G) LD(g + 2, LA0, LB0, wp0);
            if (++g >= G) break;
            CMP(LA1, LB1, wp1);
            if (g + 2 < G) LD(g + 2, LA1, LB1, wp1);
            if (++g >= G) break;
        }
    }
    // combine even-pair (H=0) and odd-pair (H=1) partial sums
    a0.x += __shfl_xor(a0.x, 32); a0.y += __shfl_xor(a0.y, 32);
    a0.z += __shfl_xor(a0.z, 32); a0.w += __shfl_xor(a0.w, 32);
    a1.x += __shfl_xor(a1.x, 32); a1.y += __shfl_xor(a1.y, 32);
    a1.z += __shfl_xor(a1.z, 32); a1.w += __shfl_xor(a1.w, 32);
    if (H == 0) {
        float inv = 1.f / (den1[n * 4 + h] + 1e-16f);
        float4 bb0 = *(const float4*)(b1 + l5 * 8);
        float4 bb1 = *(const float4*)(b1 + l5 * 8 + 4);
        float r0 = a0.x * inv + bb0.x, r1 = a0.y * inv + bb0.y;
        float r2 = a0.z * inv + bb0.z, r3 = a0.w * inv + bb0.w;
        float r4 = a1.x * inv + bb1.x, r5 = a1.y * inv + bb1.y;
        float r6 = a1.z * inv + bb1.z, r7 = a1.w * inv + bb1.w;
        r0 = r0 > 0.f ? r0 : expm1f(r0); r1 = r1 > 0.f ? r1 : expm1f(r1);
        r2 = r2 > 0.f ? r2 : expm1f(r2); r3 = r3 > 0.f ? r3 : expm1f(r3);
        r4 = r4 > 0.f ? r4 : expm1f(r4); r5 = r5 > 0.f ? r5 : expm1f(r5);
        r6 = r6 > 0.f ? r6 : expm1f(r6); r7 = r7 > 0.f ? r7 : expm1f(r7);
        uint4 st;
        st.x = (unsigned)f2bf(r0) | ((unsigned)f2bf(r1) << 16);
        st.y = (unsigned)f2bf(r2) | ((unsigned)f2bf(r3) << 16);
        st.z = (unsigned)f2bf(r4) | ((unsigned)f2bf(r5) << 16);
        st.w = (unsigned)f2bf(r6) | ((unsigned)f2bf(r7) << 16);
        *(uint4*)(void*)(h2b + (size_t)n * 256 + l5 * 8) = st;
    }
}

// ---------------- layer-2 aggregation: same structure, 2 channels/lane -----------------
__global__ __launch_bounds__(256, 4) void agg2_kernel(
        const unsigned short* __restrict__ g2b, const int* __restrict__ row_ptr,
        const unsigned short* __restrict__ csr_src, const unsigned short* __restrict__ w2t,
        const float* __restrict__ den2, const float* __restrict__ b2,
        float* __restrict__ out) {
    __shared__ unsigned ssrc32[4][32];
    int tid = threadIdx.x;
    int wv = tid >> 6, lane = tid & 63;
    int n = blockIdx.x * 4 + wv;
    if (n >= NN) return;
    int start = row_ptr[n], end = row_ptr[n + 1];
    int H = lane >> 5, l5 = lane & 31;
    const unsigned short* __restrict__ gp = g2b + l5 * 2;
    float ax = 0.f, ay = 0.f;
    unsigned A0, B0, w0, A1, B1, w1v;
    for (int c0 = start; c0 < end; c0 += 64) {
        int m = min(64, end - c0);
        if (lane < (m >> 1))
            ssrc32[wv][lane] = *(const unsigned*)(const void*)(csr_src + c0 + 2 * lane);
        int G = m >> 2;
        auto LD = [&](int g, unsigned& A, unsigned& B, unsigned& wp) {
            unsigned both = ssrc32[wv][2 * g + H];
            int ia = (int)(both & 0xffffu), ib = (int)(both >> 16);
            A = *(const unsigned*)(const void*)(gp + ia * 64);
            B = *(const unsigned*)(const void*)(gp + ib * 64);
            wp = *(const unsigned*)(const void*)(w2t + c0 + 4 * g + 2 * H);
        };
        auto CMP = [&](unsigned A, unsigned B, unsigned wp) {
            ax = fdot2bf(prm(B, A, 0x05040100), wp, ax);
            ay = fdot2bf(prm(B, A, 0x07060302), wp, ay);
        };
        LD(0, A0, B0, w0);
        if (G > 1) LD(1, A1, B1, w1v);
        int g = 0;
        while (true) {
            CMP(A0, B0, w0);
            if (g + 2 < G) LD(g + 2, A0, B0, w0);
            if (++g >= G) break;
            CMP(A1, B1, w1v);
            if (g + 2 < G) LD(g + 2, A1, B1, w1v);
            if (++g >= G) break;
        }
    }
    ax += __shfl_xor(ax, 32);
    ay += __shfl_xor(ay, 32);
    if (H == 0) {
        float inv = 1.f / (den2[n] + 1e-16f);
        float2 bv = ((const float2*)b2)[l5];
        float rx = ax * inv + bv.x;
        float ry = ay * inv + bv.y;
        rx = rx > 0.f ? rx : expm1f(rx);
        ry = ry > 0.f ? ry : expm1f(ry);
        *(float2*)(out + (size_t)n * 64 + l5 * 2) = make_float2(rx, ry);
    }
}

// ---------------- launch ----------------

extern "C" void kernel_launch(void* const* d_in, const int* in_sizes, int n_in,
                              void* d_out, int out_size, void* d_ws, size_t ws_size,
                              hipStream_t stream) {
    const float* x      = (const float*)d_in[0];
    const int*   ei     = (const int*)d_in[1];
    const float* W1     = (const float*)d_in[2];
    const float* a_src1 = (const float*)d_in[3];
    const float* a_dst1 = (const float*)d_in[4];
    const float* b1     = (const float*)d_in[5];
    const float* W2     = (const float*)d_in[6];
    const float* a_src2 = (const float*)d_in[7];
    const float* a_dst2 = (const float*)d_in[8];
    const float* b2     = (const float*)d_in[9];
    float* out = (float*)d_out;

    char* base = (char*)d_ws;
    size_t off = 0;
    auto alloc = [&](size_t bytes) -> void* {
        void* p = base + off;
        off = (off + bytes + 255) & ~(size_t)255;
        return p;
    };
    // zero-initialized span: deg | desc | den1 | den2 (one memset)
    int*   deg     = (int*)alloc(NN * sizeof(int));
    unsigned long long* desc = (unsigned long long*)alloc(SCAN_BLOCKS * sizeof(unsigned long long));
    float* den1    = (float*)alloc((size_t)NN * 4 * sizeof(float));
    float* den2    = (float*)alloc((size_t)NN * sizeof(float));
    unsigned short* rank = (unsigned short*)alloc(EE * sizeof(unsigned short));
    int*   row_ptr = (int*)alloc((NN + 1) * sizeof(int));
    unsigned short* csr_src = (unsigned short*)alloc((size_t)EEP * sizeof(unsigned short));
    unsigned short* w1t = (unsigned short*)alloc((size_t)4 * EEP * sizeof(unsigned short));
    unsigned short* w2t = (unsigned short*)alloc((size_t)EEP * sizeof(unsigned short));
    unsigned short* W1Thi = (unsigned short*)alloc(256 * 128 * 2);
    unsigned short* W1Tlo = (unsigned short*)alloc(256 * 128 * 2);
    unsigned short* W2Thi = (unsigned short*)alloc(64 * 256 * 2);
    unsigned short* W2Tlo = (unsigned short*)alloc(64 * 256 * 2);
    unsigned short* h1b   = (unsigned short*)alloc((size_t)NN * 256 * 2);
    float* as1     = (float*)alloc((size_t)NN * 4 * sizeof(float));
    float* ad1     = (float*)alloc((size_t)NN * 4 * sizeof(float));
    unsigned short* h2b   = (unsigned short*)alloc((size_t)NN * 256 * 2);
    // ---- aliased regions (safe by kernel ordering) ----
    // g2b (written in gemm2) overlays h1b (last read in agg1)
    unsigned short* g2b = h1b;
    // as2/ad2 (written in gemm2) overlay as1/ad1 (last read in scatter_w1)
    float* as2 = as1;
    float* ad2 = ad1;

    size_t clear_bytes = (size_t)((char*)(den2 + NN) - (char*)deg);
    hipMemsetAsync(deg, 0, clear_bytes, stream);

    front_kernel<<<EBLOCKS + 128 + 64, 256, 0, stream>>>(ei, deg, rank, W1, W1Thi, W1Tlo,
                                                         W2, W2Thi, W2Tlo);
    scan_fill_kernel<<<SCAN_BLOCKS, 256, 0, stream>>>(deg, desc, row_ptr, csr_src, w1t, w2t);

    gemm1_mfma<<<(NN + 63) / 64, 256, 0, stream>>>(x, W1Thi, W1Tlo,
                                                   a_src1, a_dst1, h1b, as1, ad1);
    scatter_w1_kernel<<<EBLOCKS, 256, 0, stream>>>(ei, rank, row_ptr, as1, ad1,
                                                   csr_src, w1t, den1);
    agg1_kernel<<<(NN + 3) / 4, 256, 0, stream>>>(h1b, row_ptr, csr_src, w1t, den1, b1, h2b);
    gemm2_mfma<<<(NN + 127) / 128, 256, 0, stream>>>(h2b, W2Thi, W2Tlo,
                                                     a_src2, a_dst2, g2b, as2, ad2);
    w2_kernel<<<EBLOCKS, 256, 0, stream>>>(ei, rank, row_ptr, as2, ad2, w2t, den2);
    agg2_kernel<<<(NN + 3) / 4, 256, 0, stream>>>(g2b, row_ptr, csr_src, w2t, den2, b2, out);
}

// Round 4
// 290.825 us; speedup vs baseline: 1.6859x; 1.6859x over previous
//
#include <hip/hip_runtime.h>
#include <math.h>

#define NN 50000
#define EE 800000
#define IN_C 128
#define HID 64
#define HEADS 4
#define EEP 950000                       // padded CSR capacity: EE + 3*NN (rows padded to %4)
#define SCAN_BLOCKS ((NN + 255) / 256)   // 196
#define EBLOCKS ((EE + 255) / 256)       // 3125

typedef __attribute__((ext_vector_type(8))) short bf16x8;
typedef __attribute__((ext_vector_type(4))) float f32x4;

#if defined(__has_builtin)
#if __has_builtin(__builtin_amdgcn_fdot2_f32_bf16)
#define HAVE_FDOT2_BF16 1
#endif
#endif

// ---------------- helpers ----------------

__device__ inline unsigned short f2bf(float f) {       // fp32 -> bf16 RNE
    unsigned u = __float_as_uint(f);
    return (unsigned short)((u + 0x7fff + ((u >> 16) & 1)) >> 16);
}
__device__ inline float bf2f(unsigned short s) {
    return __uint_as_float(((unsigned)s) << 16);
}
__device__ inline unsigned prm(unsigned a, unsigned b, unsigned sel) {
    return __builtin_amdgcn_perm(a, b, sel);
}
#ifdef HAVE_FDOT2_BF16
typedef __attribute__((ext_vector_type(2))) __bf16 bf2v;
__device__ inline float fdot2bf(unsigned h, unsigned w, float acc) {
    return __builtin_amdgcn_fdot2_f32_bf16(__builtin_bit_cast(bf2v, h),
                                           __builtin_bit_cast(bf2v, w), acc, false);
}
#else
__device__ inline float fdot2bf(unsigned h, unsigned w, float acc) {
    return acc + bf2f((unsigned short)(h & 0xffff)) * bf2f((unsigned short)(w & 0xffff))
               + bf2f((unsigned short)(h >> 16)) * bf2f((unsigned short)(w >> 16));
}
#endif

__device__ inline int wave_incl_scan(int v, int lane) {
    #pragma unroll
    for (int off = 1; off < 64; off <<= 1) {
        int t = __shfl_up(v, off);
        if (lane >= off) v += t;
    }
    return v;
}

__device__ inline int block256_excl_scan(int v, int tid, int* ws4) {
    int lane = tid & 63, wv = tid >> 6;
    int incl = wave_incl_scan(v, lane);
    if (lane == 63) ws4[wv] = incl;
    __syncthreads();
    if (tid == 0) {
        int run = 0;
        #pragma unroll
        for (int i = 0; i < 4; i++) { int t = ws4[i]; ws4[i] = run; run += t; }
    }
    __syncthreads();
    return incl + ws4[wv] - v;
}

// ---------------- front: degree histogram (+edge ranks) + weight splits ----------------

__global__ void front_kernel(const int* __restrict__ ei, int* __restrict__ deg,
                             unsigned short* __restrict__ rank,
                             const float* __restrict__ W1, unsigned short* __restrict__ W1Thi,
                             unsigned short* __restrict__ W1Tlo,
                             const float* __restrict__ W2, unsigned short* __restrict__ W2Thi,
                             unsigned short* __restrict__ W2Tlo) {
    int b = blockIdx.x;
    int tid = threadIdx.x;
    if (b < EBLOCKS) {
        int i = b * 256 + tid;
        if (i < EE) rank[i] = (unsigned short)atomicAdd(&deg[ei[EE + i]], 1);
    } else if (b < EBLOCKS + 128) {
        int idx = (b - EBLOCKS) * 256 + tid;         // W1 [128][256]
        int r = idx >> 8, c = idx & 255;
        float v = W1[idx];
        unsigned short h = f2bf(v);
        W1Thi[c * 128 + r] = h;
        W1Tlo[c * 128 + r] = f2bf(v - bf2f(h));
    } else {
        int idx = (b - EBLOCKS - 128) * 256 + tid;   // W2 [256][64]
        int r = idx >> 6, c = idx & 63;
        float v = W2[idx];
        unsigned short h = f2bf(v);
        W2Thi[c * 256 + r] = h;
        W2Tlo[c * 256 + r] = f2bf(v - bf2f(h));
    }
}

// ---------------- single-pass CSR scan (decoupled lookback), rows padded to %4 ----------
// Zeroes csr_src pad slots (id 0) so the gather reads stay in-bounds; pad weights are
// forced to zero in the agg kernels via the real-degree guard.
__global__ void scan_fill_kernel(const int* __restrict__ deg,
                                 unsigned long long* __restrict__ desc,
                                 int* __restrict__ row_ptr,
                                 unsigned short* __restrict__ csr_src) {
    __shared__ int ws4[4];
    __shared__ int sbase;
    int b = blockIdx.x, tid = threadIdx.x;
    int idx = b * 256 + tid;
    int draw = (idx < NN) ? deg[idx] : 0;
    int d = (draw + 3) & ~3;                 // pad each row to multiple of 4
    int excl = block256_excl_scan(d, tid, ws4);
    if (tid == 255) {
        unsigned total = (unsigned)(excl + d);
        __threadfence();
        atomicExch(&desc[b], (1ULL << 32) | (unsigned long long)total);
    }
    if (tid < 64) {
        int sum = 0;
        int hi = b;
        while (hi > 0) {
            int lo = hi - 64; if (lo < 0) lo = 0;
            int myi = lo + tid;
            unsigned v = 0;
            if (myi < hi) {
                unsigned long long d8;
                do { d8 = atomicAdd(&desc[myi], 0ULL); } while ((d8 >> 32) == 0);
                v = (unsigned)(d8 & 0xffffffffULL);
            }
            #pragma unroll
            for (int off = 32; off; off >>= 1) v += __shfl_down(v, off);
            v = __shfl(v, 0);
            sum += (int)v;
            hi = lo;
        }
        if (tid == 0) sbase = sum;
    }
    __syncthreads();
    int gbase = sbase;
    if (idx < NN) {
        int rp = gbase + excl;
        row_ptr[idx] = rp;
        for (int p = rp + draw; p < rp + d; ++p) csr_src[p] = 0;   // pad ids -> node 0
    }
    if (b == gridDim.x - 1 && tid == 255) row_ptr[NN] = gbase + excl + d;
}

// atomic-free scatter: position = row_ptr[dst] + precomputed rank (u16 ids)
__global__ void scatter_kernel(const int* __restrict__ ei, const unsigned short* __restrict__ rank,
                               const int* __restrict__ row_ptr, unsigned short* __restrict__ csr_src) {
    int i = blockIdx.x * blockDim.x + threadIdx.x;
    if (i < EE) {
        int d = ei[EE + i];
        csr_src[row_ptr[d] + (int)rank[i]] = (unsigned short)ei[i];
    }
}

// ---------------- layer-1 MFMA GEMM + fused alpha ----------------
__global__ __launch_bounds__(256) void gemm1_mfma(
        const float* __restrict__ x,
        const unsigned short* __restrict__ Bhi, const unsigned short* __restrict__ Blo,
        const float* __restrict__ a_src, const float* __restrict__ a_dst,
        unsigned short* __restrict__ h1b, float* __restrict__ as1, float* __restrict__ ad1) {
    __shared__ unsigned short Ahi[64][136];   // +8 pad
    __shared__ unsigned short Alo[64][136];
    int tid = threadIdx.x;
    int w = tid >> 6, lane = tid & 63;
    int lq = lane >> 4, lr = lane & 15;
    int brow = blockIdx.x * 64;
    {
        int row = tid >> 2;                    // 0..63
        int col0 = (tid & 3) * 32;             // 0,32,64,96
        int gr = min(brow + row, NN - 1);
        #pragma unroll
        for (int i = 0; i < 32; i += 4) {
            float4 v = *(const float4*)(x + (size_t)gr * 128 + col0 + i);
            unsigned short h0 = f2bf(v.x), h1 = f2bf(v.y), h2 = f2bf(v.z), h3 = f2bf(v.w);
            Ahi[row][col0 + i + 0] = h0; Alo[row][col0 + i + 0] = f2bf(v.x - bf2f(h0));
            Ahi[row][col0 + i + 1] = h1; Alo[row][col0 + i + 1] = f2bf(v.y - bf2f(h1));
            Ahi[row][col0 + i + 2] = h2; Alo[row][col0 + i + 2] = f2bf(v.z - bf2f(h2));
            Ahi[row][col0 + i + 3] = h3; Alo[row][col0 + i + 3] = f2bf(v.w - bf2f(h3));
        }
    }
    __syncthreads();
    f32x4 acc[4][4];
    f32x4 zf = {0.f, 0.f, 0.f, 0.f};
    #pragma unroll
    for (int mi = 0; mi < 4; mi++)
        #pragma unroll
        for (int ni = 0; ni < 4; ni++) acc[mi][ni] = zf;
    #pragma unroll
    for (int q = 0; q < 4; q++) {
        int ko = q * 32 + lq * 8;
        bf16x8 ah[4], al[4];
        #pragma unroll
        for (int mi = 0; mi < 4; mi++) {
            ah[mi] = *(const bf16x8*)(const void*)&Ahi[mi * 16 + lr][ko];
            al[mi] = *(const bf16x8*)(const void*)&Alo[mi * 16 + lr][ko];
        }
        #pragma unroll
        for (int ni = 0; ni < 4; ni++) {
            size_t bo = (size_t)(w * 64 + ni * 16 + lr) * 128 + ko;
            bf16x8 bh = *(const bf16x8*)(const void*)(Bhi + bo);
            bf16x8 bl = *(const bf16x8*)(const void*)(Blo + bo);
            #pragma unroll
            for (int mi = 0; mi < 4; mi++) {
                acc[mi][ni] = __builtin_amdgcn_mfma_f32_16x16x32_bf16(al[mi], bh, acc[mi][ni], 0, 0, 0);
                acc[mi][ni] = __builtin_amdgcn_mfma_f32_16x16x32_bf16(ah[mi], bl, acc[mi][ni], 0, 0, 0);
                acc[mi][ni] = __builtin_amdgcn_mfma_f32_16x16x32_bf16(ah[mi], bh, acc[mi][ni], 0, 0, 0);
            }
        }
    }
    float asv[4], adv[4];
    #pragma unroll
    for (int ni = 0; ni < 4; ni++) {
        asv[ni] = a_src[w * 64 + ni * 16 + lr];
        adv[ni] = a_dst[w * 64 + ni * 16 + lr];
    }
    #pragma unroll
    for (int mi = 0; mi < 4; mi++) {
        f32x4 ps = zf, pd = zf;
        #pragma unroll
        for (int ni = 0; ni < 4; ni++)
            #pragma unroll
            for (int r = 0; r < 4; r++) {
                ps[r] += acc[mi][ni][r] * asv[ni];
                pd[r] += acc[mi][ni][r] * adv[ni];
            }
        #pragma unroll
        for (int m = 1; m < 16; m <<= 1)
            #pragma unroll
            for (int r = 0; r < 4; r++) {
                ps[r] += __shfl_xor(ps[r], m);
                pd[r] += __shfl_xor(pd[r], m);
            }
        #pragma unroll
        for (int r = 0; r < 4; r++) {
            int n = brow + mi * 16 + lq * 4 + r;
            if (lr == 0 && n < NN) { as1[n * 4 + w] = ps[r]; ad1[n * 4 + w] = pd[r]; }
        }
        #pragma unroll
        for (int ni = 0; ni < 4; ni++)
            #pragma unroll
            for (int r = 0; r < 4; r++) {
                int n = brow + mi * 16 + lq * 4 + r;
                if (n < NN)
                    h1b[(size_t)n * 256 + w * 64 + ni * 16 + lr] = f2bf(acc[mi][ni][r]);
            }
    }
}

// ---------------- layer-2 MFMA GEMM + fused alpha (single-bf16 A) ----------------
__global__ __launch_bounds__(256) void gemm2_mfma(
        const unsigned short* __restrict__ Ab,
        const unsigned short* __restrict__ Bhi, const unsigned short* __restrict__ Blo,
        const float* __restrict__ a_src, const float* __restrict__ a_dst,
        unsigned short* __restrict__ g2b, float* __restrict__ as2, float* __restrict__ ad2) {
    int tid = threadIdx.x;
    int w = tid >> 6, lane = tid & 63;
    int lq = lane >> 4, lr = lane & 15;
    int wrow = blockIdx.x * 128 + w * 32;
    f32x4 acc[2][4];
    f32x4 zf = {0.f, 0.f, 0.f, 0.f};
    #pragma unroll
    for (int mi = 0; mi < 2; mi++)
        #pragma unroll
        for (int ni = 0; ni < 4; ni++) acc[mi][ni] = zf;
    int ra = min(wrow + lr, NN - 1);
    int rb = min(wrow + 16 + lr, NN - 1);
    #pragma unroll
    for (int q = 0; q < 8; q++) {
        int ko = q * 32 + lq * 8;
        bf16x8 ah0 = *(const bf16x8*)(const void*)(Ab + (size_t)ra * 256 + ko);
        bf16x8 ah1 = *(const bf16x8*)(const void*)(Ab + (size_t)rb * 256 + ko);
        #pragma unroll
        for (int ni = 0; ni < 4; ni++) {
            size_t bo = (size_t)(ni * 16 + lr) * 256 + ko;
            bf16x8 bh = *(const bf16x8*)(const void*)(Bhi + bo);
            bf16x8 bl = *(const bf16x8*)(const void*)(Blo + bo);
            acc[0][ni] = __builtin_amdgcn_mfma_f32_16x16x32_bf16(ah0, bl, acc[0][ni], 0, 0, 0);
            acc[0][ni] = __builtin_amdgcn_mfma_f32_16x16x32_bf16(ah0, bh, acc[0][ni], 0, 0, 0);
            acc[1][ni] = __builtin_amdgcn_mfma_f32_16x16x32_bf16(ah1, bl, acc[1][ni], 0, 0, 0);
            acc[1][ni] = __builtin_amdgcn_mfma_f32_16x16x32_bf16(ah1, bh, acc[1][ni], 0, 0, 0);
        }
    }
    float asv[4], adv[4];
    #pragma unroll
    for (int ni = 0; ni < 4; ni++) {
        asv[ni] = a_src[ni * 16 + lr];
        adv[ni] = a_dst[ni * 16 + lr];
    }
    #pragma unroll
    for (int mi = 0; mi < 2; mi++) {
        f32x4 ps = zf, pd = zf;
        #pragma unroll
        for (int ni = 0; ni < 4; ni++)
            #pragma unroll
            for (int r = 0; r < 4; r++) {
                ps[r] += acc[mi][ni][r] * asv[ni];
                pd[r] += acc[mi][ni][r] * adv[ni];
            }
        #pragma unroll
        for (int m = 1; m < 16; m <<= 1)
            #pragma unroll
            for (int r = 0; r < 4; r++) {
                ps[r] += __shfl_xor(ps[r], m);
                pd[r] += __shfl_xor(pd[r], m);
            }
        #pragma unroll
        for (int r = 0; r < 4; r++) {
            int n = wrow + mi * 16 + lq * 4 + r;
            if (lr == 0 && n < NN) { as2[n] = ps[r]; ad2[n] = pd[r]; }
        }
        #pragma unroll
        for (int ni = 0; ni < 4; ni++)
            #pragma unroll
            for (int r = 0; r < 4; r++) {
                int n = wrow + mi * 16 + lq * 4 + r;
                if (n < NN)
                    g2b[(size_t)n * 64 + ni * 16 + lr] = f2bf(acc[mi][ni][r]);
            }
    }
}

// ---------------- layer-1 aggregation: fused weights + half-wave paired gather ---------
// Weight math done in-wave at staging time (no HBM weight arrays, no scattered writes).
// Pair-packed weights go through dword-typed LDS (store+load same type: order visible).
__global__ __launch_bounds__(256, 4) void agg1_kernel(
        const unsigned short* __restrict__ h1b, const int* __restrict__ row_ptr,
        const int* __restrict__ deg, const unsigned short* __restrict__ csr_src,
        const float* __restrict__ as, const float* __restrict__ ad,
        const float* __restrict__ b1, unsigned short* __restrict__ h2b) {
    __shared__ unsigned ssrc32[4][32];
    __shared__ unsigned wpk[4][4][33];             // +1 pad: head-stride off bank 0
    int tid = threadIdx.x;
    int wv = tid >> 6, lane = tid & 63;
    int n = blockIdx.x * 4 + wv;
    if (n >= NN) return;
    int start = row_ptr[n], end = row_ptr[n + 1];
    int real_end = start + deg[n];
    int H = lane >> 5, l5 = lane & 31;
    int h = l5 >> 3;                               // head of this lane's 8 channels
    const unsigned short* __restrict__ hp = h1b + l5 * 8;
    float4 adv = ((const float4*)ad)[n];
    f32x4 a0 = {0.f, 0.f, 0.f, 0.f}, a1 = {0.f, 0.f, 0.f, 0.f};
    float d0 = 0.f, d1 = 0.f, d2 = 0.f, d3 = 0.f;
    uint4 LA0, LB0, LA1, LB1;
    unsigned wp0, wp1;
    for (int c0 = start; c0 < end; c0 += 64) {
        int m = min(64, end - c0);                 // multiple of 4 (padded rows)
        if (lane < (m >> 1))                       // stage packed src-id pairs as dwords
            ssrc32[wv][lane] = *(const unsigned*)(const void*)(csr_src + c0 + 2 * lane);
        // fused weight computation (full precision denominators, baseline numerics)
        float x0 = 0.f, x1 = 0.f, x2 = 0.f, x3 = 0.f;
        if (c0 + lane < real_end) {
            int s = (int)csr_src[c0 + lane];
            float4 av = ((const float4*)as)[s];
            float e0 = av.x + adv.x; e0 = e0 > 0.f ? e0 : 0.2f * e0; x0 = __expf(e0);
            float e1 = av.y + adv.y; e1 = e1 > 0.f ? e1 : 0.2f * e1; x1 = __expf(e1);
            float e2 = av.z + adv.z; e2 = e2 > 0.f ? e2 : 0.2f * e2; x2 = __expf(e2);
            float e3 = av.w + adv.w; e3 = e3 > 0.f ? e3 : 0.2f * e3; x3 = __expf(e3);
            d0 += x0; d1 += x1; d2 += x2; d3 += x3;
        }
        unsigned p0 = f2bf(x0), p1 = f2bf(x1), p2 = f2bf(x2), p3 = f2bf(x3);
        unsigned q0 = (unsigned)__shfl_down((int)p0, 1);
        unsigned q1 = (unsigned)__shfl_down((int)p1, 1);
        unsigned q2 = (unsigned)__shfl_down((int)p2, 1);
        unsigned q3 = (unsigned)__shfl_down((int)p3, 1);
        if (((lane & 1) == 0) && lane < m) {
            wpk[wv][0][lane >> 1] = p0 | (q0 << 16);
            wpk[wv][1][lane >> 1] = p1 | (q1 << 16);
            wpk[wv][2][lane >> 1] = p2 | (q2 << 16);
            wpk[wv][3][lane >> 1] = p3 | (q3 << 16);
        }
        int G = m >> 2;
        auto LD = [&](int g, uint4& A, uint4& B, unsigned& wp) {
            unsigned both = ssrc32[wv][2 * g + H];
            int ia = (int)(both & 0xffffu), ib = (int)(both >> 16);
            A = *(const uint4*)(const void*)(hp + ia * 256);
            B = *(const uint4*)(const void*)(hp + ib * 256);
            wp = wpk[wv][h][2 * g + H];
        };
        auto CMP = [&](const uint4& A, const uint4& B, unsigned wp) {
            a0.x = fdot2bf(prm(B.x, A.x, 0x05040100), wp, a0.x);
            a0.y = fdot2bf(prm(B.x, A.x, 0x07060302), wp, a0.y);
            a0.z = fdot2bf(prm(B.y, A.y, 0x05040100), wp, a0.z);
            a0.w = fdot2bf(prm(B.y, A.y, 0x07060302), wp, a0.w);
            a1.x = fdot2bf(prm(B.z, A.z, 0x05040100), wp, a1.x);
            a1.y = fdot2bf(prm(B.z, A.z, 0x07060302), wp, a1.y);
            a1.z = fdot2bf(prm(B.w, A.w, 0x05040100), wp, a1.z);
            a1.w = fdot2bf(prm(B.w, A.w, 0x07060302), wp, a1.w);
        };
        LD(0, LA0, LB0, wp0);
        if (G > 1) LD(1, LA1, LB1, wp1);
        int g = 0;
        while (true) {
            CMP(LA0, LB0, wp0);
            if (g + 2 < G) LD(g + 2, LA0, LB0, wp0);
            if (++g >= G) break;
            CMP(LA1, LB1, wp1);
            if (g + 2 < G) LD(g + 2, LA1, LB1, wp1);
            if (++g >= G) break;
        }
    }
    // denominator: exact fp32 sum across the wave (baseline numerics)
    #pragma unroll
    for (int off = 32; off; off >>= 1) {
        d0 += __shfl_down(d0, off); d1 += __shfl_down(d1, off);
        d2 += __shfl_down(d2, off); d3 += __shfl_down(d3, off);
    }
    d0 = __shfl(d0, 0); d1 = __shfl(d1, 0);
    d2 = __shfl(d2, 0); d3 = __shfl(d3, 0);
    float den = h == 0 ? d0 : h == 1 ? d1 : h == 2 ? d2 : d3;
    // combine even-pair (H=0) and odd-pair (H=1) partial sums
    a0.x += __shfl_xor(a0.x, 32); a0.y += __shfl_xor(a0.y, 32);
    a0.z += __shfl_xor(a0.z, 32); a0.w += __shfl_xor(a0.w, 32);
    a1.x += __shfl_xor(a1.x, 32); a1.y += __shfl_xor(a1.y, 32);
    a1.z += __shfl_xor(a1.z, 32); a1.w += __shfl_xor(a1.w, 32);
    if (H == 0) {
        float inv = 1.f / (den + 1e-16f);
        float4 bb0 = *(const float4*)(b1 + l5 * 8);
        float4 bb1 = *(const float4*)(b1 + l5 * 8 + 4);
        float r0 = a0.x * inv + bb0.x, r1 = a0.y * inv + bb0.y;
        float r2 = a0.z * inv + bb0.z, r3 = a0.w * inv + bb0.w;
        float r4 = a1.x * inv + bb1.x, r5 = a1.y * inv + bb1.y;
        float r6 = a1.z * inv + bb1.z, r7 = a1.w * inv + bb1.w;
        r0 = r0 > 0.f ? r0 : expm1f(r0); r1 = r1 > 0.f ? r1 : expm1f(r1);
        r2 = r2 > 0.f ? r2 : expm1f(r2); r3 = r3 > 0.f ? r3 : expm1f(r3);
        r4 = r4 > 0.f ? r4 : expm1f(r4); r5 = r5 > 0.f ? r5 : expm1f(r5);
        r6 = r6 > 0.f ? r6 : expm1f(r6); r7 = r7 > 0.f ? r7 : expm1f(r7);
        uint4 st;
        st.x = (unsigned)f2bf(r0) | ((unsigned)f2bf(r1) << 16);
        st.y = (unsigned)f2bf(r2) | ((unsigned)f2bf(r3) << 16);
        st.z = (unsigned)f2bf(r4) | ((unsigned)f2bf(r5) << 16);
        st.w = (unsigned)f2bf(r6) | ((unsigned)f2bf(r7) << 16);
        *(uint4*)(void*)(h2b + (size_t)n * 256 + l5 * 8) = st;
    }
}

// ---------------- layer-2 aggregation: fused weights, 2 channels/lane ------------------
__global__ __launch_bounds__(256, 4) void agg2_kernel(
        const unsigned short* __restrict__ g2b, const int* __restrict__ row_ptr,
        const int* __restrict__ deg, const unsigned short* __restrict__ csr_src,
        const float* __restrict__ as, const float* __restrict__ ad,
        const float* __restrict__ b2, float* __restrict__ out) {
    __shared__ unsigned ssrc32[4][32];
    __shared__ unsigned wpk2[4][32];
    int tid = threadIdx.x;
    int wv = tid >> 6, lane = tid & 63;
    int n = blockIdx.x * 4 + wv;
    if (n >= NN) return;
    int start = row_ptr[n], end = row_ptr[n + 1];
    int real_end = start + deg[n];
    int H = lane >> 5, l5 = lane & 31;
    const unsigned short* __restrict__ gp = g2b + l5 * 2;
    float adv = ad[n];
    float ax = 0.f, ay = 0.f;
    float dsum = 0.f;
    unsigned A0, B0, w0, A1, B1, w1v;
    for (int c0 = start; c0 < end; c0 += 64) {
        int m = min(64, end - c0);
        if (lane < (m >> 1))
            ssrc32[wv][lane] = *(const unsigned*)(const void*)(csr_src + c0 + 2 * lane);
        float x = 0.f;
        if (c0 + lane < real_end) {
            int s = (int)csr_src[c0 + lane];
            float e = as[s] + adv;
            e = e > 0.f ? e : 0.2f * e;
            x = __expf(e);
            dsum += x;
        }
        unsigned p = f2bf(x);
        unsigned q = (unsigned)__shfl_down((int)p, 1);
        if (((lane & 1) == 0) && lane < m) wpk2[wv][lane >> 1] = p | (q << 16);
        int G = m >> 2;
        auto LD = [&](int g, unsigned& A, unsigned& B, unsigned& wp) {
            unsigned both = ssrc32[wv][2 * g + H];
            int ia = (int)(both & 0xffffu), ib = (int)(both >> 16);
            A = *(const unsigned*)(const void*)(gp + ia * 64);
            B = *(const unsigned*)(const void*)(gp + ib * 64);
            wp = wpk2[wv][2 * g + H];
        };
        auto CMP = [&](unsigned A, unsigned B, unsigned wp) {
            ax = fdot2bf(prm(B, A, 0x05040100), wp, ax);
            ay = fdot2bf(prm(B, A, 0x07060302), wp, ay);
        };
        LD(0, A0, B0, w0);
        if (G > 1) LD(1, A1, B1, w1v);
        int g = 0;
        while (true) {
            CMP(A0, B0, w0);
            if (g + 2 < G) LD(g + 2, A0, B0, w0);
            if (++g >= G) break;
            CMP(A1, B1, w1v);
            if (g + 2 < G) LD(g + 2, A1, B1, w1v);
            if (++g >= G) break;
        }
    }
    #pragma unroll
    for (int off = 32; off; off >>= 1) dsum += __shfl_down(dsum, off);
    dsum = __shfl(dsum, 0);
    ax += __shfl_xor(ax, 32);
    ay += __shfl_xor(ay, 32);
    if (H == 0) {
        float inv = 1.f / (dsum + 1e-16f);
        float2 bv = ((const float2*)b2)[l5];
        float rx = ax * inv + bv.x;
        float ry = ay * inv + bv.y;
        rx = rx > 0.f ? rx : expm1f(rx);
        ry = ry > 0.f ? ry : expm1f(ry);
        *(float2*)(out + (size_t)n * 64 + l5 * 2) = make_float2(rx, ry);
    }
}

// ---------------- launch ----------------

extern "C" void kernel_launch(void* const* d_in, const int* in_sizes, int n_in,
                              void* d_out, int out_size, void* d_ws, size_t ws_size,
                              hipStream_t stream) {
    const float* x      = (const float*)d_in[0];
    const int*   ei     = (const int*)d_in[1];
    const float* W1     = (const float*)d_in[2];
    const float* a_src1 = (const float*)d_in[3];
    const float* a_dst1 = (const float*)d_in[4];
    const float* b1     = (const float*)d_in[5];
    const float* W2     = (const float*)d_in[6];
    const float* a_src2 = (const float*)d_in[7];
    const float* a_dst2 = (const float*)d_in[8];
    const float* b2     = (const float*)d_in[9];
    float* out = (float*)d_out;

    char* base = (char*)d_ws;
    size_t off = 0;
    auto alloc = [&](size_t bytes) -> void* {
        void* p = base + off;
        off = (off + bytes + 255) & ~(size_t)255;
        return p;
    };
    // zero-initialized span: deg | desc (one memset)
    int*   deg     = (int*)alloc(NN * sizeof(int));
    unsigned long long* desc = (unsigned long long*)alloc(SCAN_BLOCKS * sizeof(unsigned long long));
    unsigned short* rank = (unsigned short*)alloc(EE * sizeof(unsigned short));
    int*   row_ptr = (int*)alloc((NN + 1) * sizeof(int));
    unsigned short* csr_src = (unsigned short*)alloc((size_t)EEP * sizeof(unsigned short));
    unsigned short* W1Thi = (unsigned short*)alloc(256 * 128 * 2);
    unsigned short* W1Tlo = (unsigned short*)alloc(256 * 128 * 2);
    unsigned short* W2Thi = (unsigned short*)alloc(64 * 256 * 2);
    unsigned short* W2Tlo = (unsigned short*)alloc(64 * 256 * 2);
    unsigned short* h1b   = (unsigned short*)alloc((size_t)NN * 256 * 2);
    float* as1     = (float*)alloc((size_t)NN * 4 * sizeof(float));
    float* ad1     = (float*)alloc((size_t)NN * 4 * sizeof(float));
    unsigned short* h2b   = (unsigned short*)alloc((size_t)NN * 256 * 2);
    // ---- aliased regions (safe by kernel ordering) ----
    // g2b (written in gemm2) overlays h1b (last read in agg1)
    unsigned short* g2b = h1b;
    // as2/ad2 (written in gemm2) overlay as1/ad1 (last read in agg1)
    float* as2 = as1;
    float* ad2 = ad1;

    size_t clear_bytes = (size_t)((char*)(desc + SCAN_BLOCKS) - (char*)deg);
    hipMemsetAsync(deg, 0, clear_bytes, stream);

    front_kernel<<<EBLOCKS + 128 + 64, 256, 0, stream>>>(ei, deg, rank, W1, W1Thi, W1Tlo,
                                                         W2, W2Thi, W2Tlo);
    scan_fill_kernel<<<SCAN_BLOCKS, 256, 0, stream>>>(deg, desc, row_ptr, csr_src);
    scatter_kernel<<<EBLOCKS, 256, 0, stream>>>(ei, rank, row_ptr, csr_src);

    gemm1_mfma<<<(NN + 63) / 64, 256, 0, stream>>>(x, W1Thi, W1Tlo,
                                                   a_src1, a_dst1, h1b, as1, ad1);
    agg1_kernel<<<(NN + 3) / 4, 256, 0, stream>>>(h1b, row_ptr, deg, csr_src,
                                                  as1, ad1, b1, h2b);
    gemm2_mfma<<<(NN + 127) / 128, 256, 0, stream>>>(h2b, W2Thi, W2Tlo,
                                                     a_src2, a_dst2, g2b, as2, ad2);
    agg2_kernel<<<(NN + 3) / 4, 256, 0, stream>>>(g2b, row_ptr, deg, csr_src,
                                                  as2, ad2, b2, out);
}

// Round 5
// 285.173 us; speedup vs baseline: 1.7193x; 1.0198x over previous
//
#include <hip/hip_runtime.h>
#include <math.h>

#define NN 50000
#define EE 800000
#define IN_C 128
#define HID 64
#define HEADS 4
#define EEP 950000                       // padded CSR capacity: EE + 3*NN (rows padded to %4)
#define SCAN_BLOCKS ((NN + 255) / 256)   // 196
#define EBLOCKS ((EE + 255) / 256)       // 3125

typedef __attribute__((ext_vector_type(8))) short bf16x8;
typedef __attribute__((ext_vector_type(4))) float f32x4;

#if defined(__has_builtin)
#if __has_builtin(__builtin_amdgcn_fdot2_f32_bf16)
#define HAVE_FDOT2_BF16 1
#endif
#endif

// ---------------- helpers ----------------

__device__ inline unsigned short f2bf(float f) {       // fp32 -> bf16 RNE
    unsigned u = __float_as_uint(f);
    return (unsigned short)((u + 0x7fff + ((u >> 16) & 1)) >> 16);
}
__device__ inline float bf2f(unsigned short s) {
    return __uint_as_float(((unsigned)s) << 16);
}
__device__ inline unsigned prm(unsigned a, unsigned b, unsigned sel) {
    return __builtin_amdgcn_perm(a, b, sel);
}
#ifdef HAVE_FDOT2_BF16
typedef __attribute__((ext_vector_type(2))) __bf16 bf2v;
__device__ inline float fdot2bf(unsigned h, unsigned w, float acc) {
    return __builtin_amdgcn_fdot2_f32_bf16(__builtin_bit_cast(bf2v, h),
                                           __builtin_bit_cast(bf2v, w), acc, false);
}
#else
__device__ inline float fdot2bf(unsigned h, unsigned w, float acc) {
    return acc + bf2f((unsigned short)(h & 0xffff)) * bf2f((unsigned short)(w & 0xffff))
               + bf2f((unsigned short)(h >> 16)) * bf2f((unsigned short)(w >> 16));
}
#endif

__device__ inline int wave_incl_scan(int v, int lane) {
    #pragma unroll
    for (int off = 1; off < 64; off <<= 1) {
        int t = __shfl_up(v, off);
        if (lane >= off) v += t;
    }
    return v;
}

__device__ inline int block256_excl_scan(int v, int tid, int* ws4) {
    int lane = tid & 63, wv = tid >> 6;
    int incl = wave_incl_scan(v, lane);
    if (lane == 63) ws4[wv] = incl;
    __syncthreads();
    if (tid == 0) {
        int run = 0;
        #pragma unroll
        for (int i = 0; i < 4; i++) { int t = ws4[i]; ws4[i] = run; run += t; }
    }
    __syncthreads();
    return incl + ws4[wv] - v;
}

// ---------------- front: degree histogram (+edge ranks) + weight splits ----------------

__global__ void front_kernel(const int* __restrict__ ei, int* __restrict__ deg,
                             unsigned short* __restrict__ rank,
                             const float* __restrict__ W1, unsigned short* __restrict__ W1Thi,
                             unsigned short* __restrict__ W1Tlo,
                             const float* __restrict__ W2, unsigned short* __restrict__ W2Thi,
                             unsigned short* __restrict__ W2Tlo) {
    int b = blockIdx.x;
    int tid = threadIdx.x;
    if (b < EBLOCKS) {
        int i = b * 256 + tid;
        if (i < EE) rank[i] = (unsigned short)atomicAdd(&deg[ei[EE + i]], 1);
    } else if (b < EBLOCKS + 128) {
        int idx = (b - EBLOCKS) * 256 + tid;         // W1 [128][256]
        int r = idx >> 8, c = idx & 255;
        float v = W1[idx];
        unsigned short h = f2bf(v);
        W1Thi[c * 128 + r] = h;
        W1Tlo[c * 128 + r] = f2bf(v - bf2f(h));
    } else {
        int idx = (b - EBLOCKS - 128) * 256 + tid;   // W2 [256][64]
        int r = idx >> 6, c = idx & 63;
        float v = W2[idx];
        unsigned short h = f2bf(v);
        W2Thi[c * 256 + r] = h;
        W2Tlo[c * 256 + r] = f2bf(v - bf2f(h));
    }
}

// ---------------- single-pass CSR scan (decoupled lookback), rows padded to %4 ----------
__global__ void scan_fill_kernel(const int* __restrict__ deg,
                                 unsigned long long* __restrict__ desc,
                                 int* __restrict__ row_ptr,
                                 unsigned short* __restrict__ csr_src) {
    __shared__ int ws4[4];
    __shared__ int sbase;
    int b = blockIdx.x, tid = threadIdx.x;
    int idx = b * 256 + tid;
    int draw = (idx < NN) ? deg[idx] : 0;
    int d = (draw + 3) & ~3;                 // pad each row to multiple of 4
    int excl = block256_excl_scan(d, tid, ws4);
    if (tid == 255) {
        unsigned total = (unsigned)(excl + d);
        __threadfence();
        atomicExch(&desc[b], (1ULL << 32) | (unsigned long long)total);
    }
    if (tid < 64) {
        int sum = 0;
        int hi = b;
        while (hi > 0) {
            int lo = hi - 64; if (lo < 0) lo = 0;
            int myi = lo + tid;
            unsigned v = 0;
            if (myi < hi) {
                unsigned long long d8;
                do { d8 = atomicAdd(&desc[myi], 0ULL); } while ((d8 >> 32) == 0);
                v = (unsigned)(d8 & 0xffffffffULL);
            }
            #pragma unroll
            for (int off = 32; off; off >>= 1) v += __shfl_down(v, off);
            v = __shfl(v, 0);
            sum += (int)v;
            hi = lo;
        }
        if (tid == 0) sbase = sum;
    }
    __syncthreads();
    int gbase = sbase;
    if (idx < NN) {
        int rp = gbase + excl;
        row_ptr[idx] = rp;
        for (int p = rp + draw; p < rp + d; ++p) csr_src[p] = 0;   // pad ids -> node 0
    }
    if (b == gridDim.x - 1 && tid == 255) row_ptr[NN] = gbase + excl + d;
}

// atomic-free scatter: position = row_ptr[dst] + precomputed rank (u16 ids)
__global__ void scatter_kernel(const int* __restrict__ ei, const unsigned short* __restrict__ rank,
                               const int* __restrict__ row_ptr, unsigned short* __restrict__ csr_src) {
    int i = blockIdx.x * blockDim.x + threadIdx.x;
    if (i < EE) {
        int d = ei[EE + i];
        csr_src[row_ptr[d] + (int)rank[i]] = (unsigned short)ei[i];
    }
}

// ---------------- layer-1 MFMA GEMM + fused alpha ----------------
__global__ __launch_bounds__(256) void gemm1_mfma(
        const float* __restrict__ x,
        const unsigned short* __restrict__ Bhi, const unsigned short* __restrict__ Blo,
        const float* __restrict__ a_src, const float* __restrict__ a_dst,
        unsigned short* __restrict__ h1b, float* __restrict__ as1, float* __restrict__ ad1) {
    __shared__ unsigned short Ahi[64][136];   // +8 pad
    __shared__ unsigned short Alo[64][136];
    int tid = threadIdx.x;
    int w = tid >> 6, lane = tid & 63;
    int lq = lane >> 4, lr = lane & 15;
    int brow = blockIdx.x * 64;
    {
        int row = tid >> 2;                    // 0..63
        int col0 = (tid & 3) * 32;             // 0,32,64,96
        int gr = min(brow + row, NN - 1);
        #pragma unroll
        for (int i = 0; i < 32; i += 4) {
            float4 v = *(const float4*)(x + (size_t)gr * 128 + col0 + i);
            unsigned short h0 = f2bf(v.x), h1 = f2bf(v.y), h2 = f2bf(v.z), h3 = f2bf(v.w);
            Ahi[row][col0 + i + 0] = h0; Alo[row][col0 + i + 0] = f2bf(v.x - bf2f(h0));
            Ahi[row][col0 + i + 1] = h1; Alo[row][col0 + i + 1] = f2bf(v.y - bf2f(h1));
            Ahi[row][col0 + i + 2] = h2; Alo[row][col0 + i + 2] = f2bf(v.z - bf2f(h2));
            Ahi[row][col0 + i + 3] = h3; Alo[row][col0 + i + 3] = f2bf(v.w - bf2f(h3));
        }
    }
    __syncthreads();
    f32x4 acc[4][4];
    f32x4 zf = {0.f, 0.f, 0.f, 0.f};
    #pragma unroll
    for (int mi = 0; mi < 4; mi++)
        #pragma unroll
        for (int ni = 0; ni < 4; ni++) acc[mi][ni] = zf;
    #pragma unroll
    for (int q = 0; q < 4; q++) {
        int ko = q * 32 + lq * 8;
        bf16x8 ah[4], al[4];
        #pragma unroll
        for (int mi = 0; mi < 4; mi++) {
            ah[mi] = *(const bf16x8*)(const void*)&Ahi[mi * 16 + lr][ko];
            al[mi] = *(const bf16x8*)(const void*)&Alo[mi * 16 + lr][ko];
        }
        #pragma unroll
        for (int ni = 0; ni < 4; ni++) {
            size_t bo = (size_t)(w * 64 + ni * 16 + lr) * 128 + ko;
            bf16x8 bh = *(const bf16x8*)(const void*)(Bhi + bo);
            bf16x8 bl = *(const bf16x8*)(const void*)(Blo + bo);
            #pragma unroll
            for (int mi = 0; mi < 4; mi++) {
                acc[mi][ni] = __builtin_amdgcn_mfma_f32_16x16x32_bf16(al[mi], bh, acc[mi][ni], 0, 0, 0);
                acc[mi][ni] = __builtin_amdgcn_mfma_f32_16x16x32_bf16(ah[mi], bl, acc[mi][ni], 0, 0, 0);
                acc[mi][ni] = __builtin_amdgcn_mfma_f32_16x16x32_bf16(ah[mi], bh, acc[mi][ni], 0, 0, 0);
            }
        }
    }
    float asv[4], adv[4];
    #pragma unroll
    for (int ni = 0; ni < 4; ni++) {
        asv[ni] = a_src[w * 64 + ni * 16 + lr];
        adv[ni] = a_dst[w * 64 + ni * 16 + lr];
    }
    #pragma unroll
    for (int mi = 0; mi < 4; mi++) {
        f32x4 ps = zf, pd = zf;
        #pragma unroll
        for (int ni = 0; ni < 4; ni++)
            #pragma unroll
            for (int r = 0; r < 4; r++) {
                ps[r] += acc[mi][ni][r] * asv[ni];
                pd[r] += acc[mi][ni][r] * adv[ni];
            }
        #pragma unroll
        for (int m = 1; m < 16; m <<= 1)
            #pragma unroll
            for (int r = 0; r < 4; r++) {
                ps[r] += __shfl_xor(ps[r], m);
                pd[r] += __shfl_xor(pd[r], m);
            }
        #pragma unroll
        for (int r = 0; r < 4; r++) {
            int n = brow + mi * 16 + lq * 4 + r;
            if (lr == 0 && n < NN) { as1[n * 4 + w] = ps[r]; ad1[n * 4 + w] = pd[r]; }
        }
        #pragma unroll
        for (int ni = 0; ni < 4; ni++)
            #pragma unroll
            for (int r = 0; r < 4; r++) {
                int n = brow + mi * 16 + lq * 4 + r;
                if (n < NN)
                    h1b[(size_t)n * 256 + w * 64 + ni * 16 + lr] = f2bf(acc[mi][ni][r]);
            }
    }
}

// ---------------- layer-2 MFMA GEMM + fused alpha (single-bf16 A) ----------------
__global__ __launch_bounds__(256) void gemm2_mfma(
        const unsigned short* __restrict__ Ab,
        const unsigned short* __restrict__ Bhi, const unsigned short* __restrict__ Blo,
        const float* __restrict__ a_src, const float* __restrict__ a_dst,
        unsigned short* __restrict__ g2b, float* __restrict__ as2, float* __restrict__ ad2) {
    int tid = threadIdx.x;
    int w = tid >> 6, lane = tid & 63;
    int lq = lane >> 4, lr = lane & 15;
    int wrow = blockIdx.x * 128 + w * 32;
    f32x4 acc[2][4];
    f32x4 zf = {0.f, 0.f, 0.f, 0.f};
    #pragma unroll
    for (int mi = 0; mi < 2; mi++)
        #pragma unroll
        for (int ni = 0; ni < 4; ni++) acc[mi][ni] = zf;
    int ra = min(wrow + lr, NN - 1);
    int rb = min(wrow + 16 + lr, NN - 1);
    #pragma unroll
    for (int q = 0; q < 8; q++) {
        int ko = q * 32 + lq * 8;
        bf16x8 ah0 = *(const bf16x8*)(const void*)(Ab + (size_t)ra * 256 + ko);
        bf16x8 ah1 = *(const bf16x8*)(const void*)(Ab + (size_t)rb * 256 + ko);
        #pragma unroll
        for (int ni = 0; ni < 4; ni++) {
            size_t bo = (size_t)(ni * 16 + lr) * 256 + ko;
            bf16x8 bh = *(const bf16x8*)(const void*)(Bhi + bo);
            bf16x8 bl = *(const bf16x8*)(const void*)(Blo + bo);
            acc[0][ni] = __builtin_amdgcn_mfma_f32_16x16x32_bf16(ah0, bl, acc[0][ni], 0, 0, 0);
            acc[0][ni] = __builtin_amdgcn_mfma_f32_16x16x32_bf16(ah0, bh, acc[0][ni], 0, 0, 0);
            acc[1][ni] = __builtin_amdgcn_mfma_f32_16x16x32_bf16(ah1, bl, acc[1][ni], 0, 0, 0);
            acc[1][ni] = __builtin_amdgcn_mfma_f32_16x16x32_bf16(ah1, bh, acc[1][ni], 0, 0, 0);
        }
    }
    float asv[4], adv[4];
    #pragma unroll
    for (int ni = 0; ni < 4; ni++) {
        asv[ni] = a_src[ni * 16 + lr];
        adv[ni] = a_dst[ni * 16 + lr];
    }
    #pragma unroll
    for (int mi = 0; mi < 2; mi++) {
        f32x4 ps = zf, pd = zf;
        #pragma unroll
        for (int ni = 0; ni < 4; ni++)
            #pragma unroll
            for (int r = 0; r < 4; r++) {
                ps[r] += acc[mi][ni][r] * asv[ni];
                pd[r] += acc[mi][ni][r] * adv[ni];
            }
        #pragma unroll
        for (int m = 1; m < 16; m <<= 1)
            #pragma unroll
            for (int r = 0; r < 4; r++) {
                ps[r] += __shfl_xor(ps[r], m);
                pd[r] += __shfl_xor(pd[r], m);
            }
        #pragma unroll
        for (int r = 0; r < 4; r++) {
            int n = wrow + mi * 16 + lq * 4 + r;
            if (lr == 0 && n < NN) { as2[n] = ps[r]; ad2[n] = pd[r]; }
        }
        #pragma unroll
        for (int ni = 0; ni < 4; ni++)
            #pragma unroll
            for (int r = 0; r < 4; r++) {
                int n = wrow + mi * 16 + lq * 4 + r;
                if (n < NN)
                    g2b[(size_t)n * 64 + ni * 16 + lr] = f2bf(acc[mi][ni][r]);
            }
    }
}

// ---------------- layer-1 aggregation: lane-distributed weights + paired gather --------
// Weight phase: lane L computes head (L>>4) of edge (L&15) -> 64 (edge,head) pairs per
// pass, full issue utilization (vs 16 active lanes x 4 heads). Denominator: one scalar
// per lane, 16-lane-group shfl_xor tree + 1 broadcast. ELU via __expf-1 (bf16 output
// makes expm1 precision irrelevant).
__global__ __launch_bounds__(256, 4) void agg1_kernel(
        const unsigned short* __restrict__ h1b, const int* __restrict__ row_ptr,
        const int* __restrict__ deg, const unsigned short* __restrict__ csr_src,
        const float* __restrict__ as, const float* __restrict__ ad,
        const float* __restrict__ b1, unsigned short* __restrict__ h2b) {
    __shared__ unsigned ssrc32[4][32];
    __shared__ unsigned wpk[4][4][33];             // +1 pad: head-stride off bank 0
    int tid = threadIdx.x;
    int wv = tid >> 6, lane = tid & 63;
    int n = blockIdx.x * 4 + wv;
    if (n >= NN) return;
    int start = row_ptr[n], end = row_ptr[n + 1];
    int real_end = start + deg[n];
    int H = lane >> 5, l5 = lane & 31;
    int h = l5 >> 3;                               // out-phase head of this lane's 8 ch
    int hW = lane >> 4;                            // weight-phase head
    int eSub = lane & 15;                          // weight-phase edge-within-pass
    const unsigned short* __restrict__ hp = h1b + l5 * 8;
    float adW = ad[(size_t)n * 4 + hW];
    f32x4 a0 = {0.f, 0.f, 0.f, 0.f}, a1 = {0.f, 0.f, 0.f, 0.f};
    float dsum = 0.f;
    uint4 LA0, LB0, LA1, LB1;
    unsigned wp0, wp1;
    for (int c0 = start; c0 < end; c0 += 64) {
        int m = min(64, end - c0);                 // multiple of 4 (padded rows)
        if (lane < (m >> 1))                       // stage packed src-id pairs as dwords
            ssrc32[wv][lane] = *(const unsigned*)(const void*)(csr_src + c0 + 2 * lane);
        // weight passes: 16 edges x 4 heads = 64 lanes each
        for (int eb = 0; eb < m; eb += 16) {
            int j = eb + eSub;
            unsigned pairw = ssrc32[wv][j >> 1];
            float x = 0.f;
            if (c0 + j < real_end) {
                int s = (int)((pairw >> ((j & 1) << 4)) & 0xffffu);
                float e = as[(size_t)s * 4 + hW] + adW;
                e = fmaxf(e, 0.f) + 0.2f * fminf(e, 0.f);
                x = __expf(e);
                dsum += x;
            }
            unsigned p = f2bf(x);
            unsigned q = (unsigned)__shfl_down((int)p, 1);
            if ((eSub & 1) == 0 && j < m) wpk[wv][hW][j >> 1] = p | (q << 16);
        }
        int G = m >> 2;
        auto LD = [&](int g, uint4& A, uint4& B, unsigned& wp) {
            unsigned both = ssrc32[wv][2 * g + H];
            int ia = (int)(both & 0xffffu), ib = (int)(both >> 16);
            A = *(const uint4*)(const void*)(hp + ia * 256);
            B = *(const uint4*)(const void*)(hp + ib * 256);
            wp = wpk[wv][h][2 * g + H];
        };
        auto CMP = [&](const uint4& A, const uint4& B, unsigned wp) {
            a0.x = fdot2bf(prm(B.x, A.x, 0x05040100), wp, a0.x);
            a0.y = fdot2bf(prm(B.x, A.x, 0x07060302), wp, a0.y);
            a0.z = fdot2bf(prm(B.y, A.y, 0x05040100), wp, a0.z);
            a0.w = fdot2bf(prm(B.y, A.y, 0x07060302), wp, a0.w);
            a1.x = fdot2bf(prm(B.z, A.z, 0x05040100), wp, a1.x);
            a1.y = fdot2bf(prm(B.z, A.z, 0x07060302), wp, a1.y);
            a1.z = fdot2bf(prm(B.w, A.w, 0x05040100), wp, a1.z);
            a1.w = fdot2bf(prm(B.w, A.w, 0x07060302), wp, a1.w);
        };
        LD(0, LA0, LB0, wp0);
        if (G > 1) LD(1, LA1, LB1, wp1);
        int g = 0;
        while (true) {
            CMP(LA0, LB0, wp0);
            if (g + 2 < G) LD(g + 2, LA0, LB0, wp0);
            if (++g >= G) break;
            CMP(LA1, LB1, wp1);
            if (g + 2 < G) LD(g + 2, LA1, LB1, wp1);
            if (++g >= G) break;
        }
    }
    // denominator: reduce within each 16-lane (head) group, broadcast to out-head lanes
    #pragma unroll
    for (int off = 1; off < 16; off <<= 1) dsum += __shfl_xor(dsum, off);
    float den = __shfl(dsum, ((lane & 31) >> 3) << 4);
    // combine even-pair (H=0) and odd-pair (H=1) partial sums
    a0.x += __shfl_xor(a0.x, 32); a0.y += __shfl_xor(a0.y, 32);
    a0.z += __shfl_xor(a0.z, 32); a0.w += __shfl_xor(a0.w, 32);
    a1.x += __shfl_xor(a1.x, 32); a1.y += __shfl_xor(a1.y, 32);
    a1.z += __shfl_xor(a1.z, 32); a1.w += __shfl_xor(a1.w, 32);
    if (H == 0) {
        float inv = 1.f / (den + 1e-16f);
        float4 bb0 = *(const float4*)(b1 + l5 * 8);
        float4 bb1 = *(const float4*)(b1 + l5 * 8 + 4);
        float r0 = a0.x * inv + bb0.x, r1 = a0.y * inv + bb0.y;
        float r2 = a0.z * inv + bb0.z, r3 = a0.w * inv + bb0.w;
        float r4 = a1.x * inv + bb1.x, r5 = a1.y * inv + bb1.y;
        float r6 = a1.z * inv + bb1.z, r7 = a1.w * inv + bb1.w;
        r0 = r0 > 0.f ? r0 : __expf(r0) - 1.f; r1 = r1 > 0.f ? r1 : __expf(r1) - 1.f;
        r2 = r2 > 0.f ? r2 : __expf(r2) - 1.f; r3 = r3 > 0.f ? r3 : __expf(r3) - 1.f;
        r4 = r4 > 0.f ? r4 : __expf(r4) - 1.f; r5 = r5 > 0.f ? r5 : __expf(r5) - 1.f;
        r6 = r6 > 0.f ? r6 : __expf(r6) - 1.f; r7 = r7 > 0.f ? r7 : __expf(r7) - 1.f;
        uint4 st;
        st.x = (unsigned)f2bf(r0) | ((unsigned)f2bf(r1) << 16);
        st.y = (unsigned)f2bf(r2) | ((unsigned)f2bf(r3) << 16);
        st.z = (unsigned)f2bf(r4) | ((unsigned)f2bf(r5) << 16);
        st.w = (unsigned)f2bf(r6) | ((unsigned)f2bf(r7) << 16);
        *(uint4*)(void*)(h2b + (size_t)n * 256 + l5 * 8) = st;
    }
}

// ---------------- layer-2 aggregation: fused weights, 2 channels/lane ------------------
__global__ __launch_bounds__(256, 4) void agg2_kernel(
        const unsigned short* __restrict__ g2b, const int* __restrict__ row_ptr,
        const int* __restrict__ deg, const unsigned short* __restrict__ csr_src,
        const float* __restrict__ as, const float* __restrict__ ad,
        const float* __restrict__ b2, float* __restrict__ out) {
    __shared__ unsigned ssrc32[4][32];
    __shared__ unsigned wpk2[4][32];
    int tid = threadIdx.x;
    int wv = tid >> 6, lane = tid & 63;
    int n = blockIdx.x * 4 + wv;
    if (n >= NN) return;
    int start = row_ptr[n], end = row_ptr[n + 1];
    int real_end = start + deg[n];
    int H = lane >> 5, l5 = lane & 31;
    const unsigned short* __restrict__ gp = g2b + l5 * 2;
    float adv = ad[n];
    float ax = 0.f, ay = 0.f;
    float dsum = 0.f;
    unsigned A0, B0, w0, A1, B1, w1v;
    for (int c0 = start; c0 < end; c0 += 64) {
        int m = min(64, end - c0);
        if (lane < (m >> 1))
            ssrc32[wv][lane] = *(const unsigned*)(const void*)(csr_src + c0 + 2 * lane);
        float x = 0.f;
        if (c0 + lane < real_end) {
            unsigned pw = ssrc32[wv][lane >> 1];
            int s = (int)((pw >> ((lane & 1) << 4)) & 0xffffu);
            float e = as[s] + adv;
            e = fmaxf(e, 0.f) + 0.2f * fminf(e, 0.f);
            x = __expf(e);
            dsum += x;
        }
        unsigned p = f2bf(x);
        unsigned q = (unsigned)__shfl_down((int)p, 1);
        if (((lane & 1) == 0) && lane < m) wpk2[wv][lane >> 1] = p | (q << 16);
        int G = m >> 2;
        auto LD = [&](int g, unsigned& A, unsigned& B, unsigned& wp) {
            unsigned both = ssrc32[wv][2 * g + H];
            int ia = (int)(both & 0xffffu), ib = (int)(both >> 16);
            A = *(const unsigned*)(const void*)(gp + ia * 64);
            B = *(const unsigned*)(const void*)(gp + ib * 64);
            wp = wpk2[wv][2 * g + H];
        };
        auto CMP = [&](unsigned A, unsigned B, unsigned wp) {
            ax = fdot2bf(prm(B, A, 0x05040100), wp, ax);
            ay = fdot2bf(prm(B, A, 0x07060302), wp, ay);
        };
        LD(0, A0, B0, w0);
        if (G > 1) LD(1, A1, B1, w1v);
        int g = 0;
        while (true) {
            CMP(A0, B0, w0);
            if (g + 2 < G) LD(g + 2, A0, B0, w0);
            if (++g >= G) break;
            CMP(A1, B1, w1v);
            if (g + 2 < G) LD(g + 2, A1, B1, w1v);
            if (++g >= G) break;
        }
    }
    #pragma unroll
    for (int off = 32; off; off >>= 1) dsum += __shfl_down(dsum, off);
    dsum = __shfl(dsum, 0);
    ax += __shfl_xor(ax, 32);
    ay += __shfl_xor(ay, 32);
    if (H == 0) {
        float inv = 1.f / (dsum + 1e-16f);
        float2 bv = ((const float2*)b2)[l5];
        float rx = ax * inv + bv.x;
        float ry = ay * inv + bv.y;
        rx = rx > 0.f ? rx : __expf(rx) - 1.f;
        ry = ry > 0.f ? ry : __expf(ry) - 1.f;
        *(float2*)(out + (size_t)n * 64 + l5 * 2) = make_float2(rx, ry);
    }
}

// ---------------- launch ----------------

extern "C" void kernel_launch(void* const* d_in, const int* in_sizes, int n_in,
                              void* d_out, int out_size, void* d_ws, size_t ws_size,
                              hipStream_t stream) {
    const float* x      = (const float*)d_in[0];
    const int*   ei     = (const int*)d_in[1];
    const float* W1     = (const float*)d_in[2];
    const float* a_src1 = (const float*)d_in[3];
    const float* a_dst1 = (const float*)d_in[4];
    const float* b1     = (const float*)d_in[5];
    const float* W2     = (const float*)d_in[6];
    const float* a_src2 = (const float*)d_in[7];
    const float* a_dst2 = (const float*)d_in[8];
    const float* b2     = (const float*)d_in[9];
    float* out = (float*)d_out;

    char* base = (char*)d_ws;
    size_t off = 0;
    auto alloc = [&](size_t bytes) -> void* {
        void* p = base + off;
        off = (off + bytes + 255) & ~(size_t)255;
        return p;
    };
    // zero-initialized span: deg | desc (one memset)
    int*   deg     = (int*)alloc(NN * sizeof(int));
    unsigned long long* desc = (unsigned long long*)alloc(SCAN_BLOCKS * sizeof(unsigned long long));
    unsigned short* rank = (unsigned short*)alloc(EE * sizeof(unsigned short));
    int*   row_ptr = (int*)alloc((NN + 1) * sizeof(int));
    unsigned short* csr_src = (unsigned short*)alloc((size_t)EEP * sizeof(unsigned short));
    unsigned short* W1Thi = (unsigned short*)alloc(256 * 128 * 2);
    unsigned short* W1Tlo = (unsigned short*)alloc(256 * 128 * 2);
    unsigned short* W2Thi = (unsigned short*)alloc(64 * 256 * 2);
    unsigned short* W2Tlo = (unsigned short*)alloc(64 * 256 * 2);
    unsigned short* h1b   = (unsigned short*)alloc((size_t)NN * 256 * 2);
    float* as1     = (float*)alloc((size_t)NN * 4 * sizeof(float));
    float* ad1     = (float*)alloc((size_t)NN * 4 * sizeof(float));
    unsigned short* h2b   = (unsigned short*)alloc((size_t)NN * 256 * 2);
    // ---- aliased regions (safe by kernel ordering) ----
    // g2b (written in gemm2) overlays h1b (last read in agg1)
    unsigned short* g2b = h1b;
    // as2/ad2 (written in gemm2) overlay as1/ad1 (last read in agg1)
    float* as2 = as1;
    float* ad2 = ad1;

    size_t clear_bytes = (size_t)((char*)(desc + SCAN_BLOCKS) - (char*)deg);
    hipMemsetAsync(deg, 0, clear_bytes, stream);

    front_kernel<<<EBLOCKS + 128 + 64, 256, 0, stream>>>(ei, deg, rank, W1, W1Thi, W1Tlo,
                                                         W2, W2Thi, W2Tlo);
    scan_fill_kernel<<<SCAN_BLOCKS, 256, 0, stream>>>(deg, desc, row_ptr, csr_src);
    scatter_kernel<<<EBLOCKS, 256, 0, stream>>>(ei, rank, row_ptr, csr_src);

    gemm1_mfma<<<(NN + 63) / 64, 256, 0, stream>>>(x, W1Thi, W1Tlo,
                                                   a_src1, a_dst1, h1b, as1, ad1);
    agg1_kernel<<<(NN + 3) / 4, 256, 0, stream>>>(h1b, row_ptr, deg, csr_src,
                                                  as1, ad1, b1, h2b);
    gemm2_mfma<<<(NN + 127) / 128, 256, 0, stream>>>(h2b, W2Thi, W2Tlo,
                                                     a_src2, a_dst2, g2b, as2, ad2);
    agg2_kernel<<<(NN + 3) / 4, 256, 0, stream>>>(g2b, row_ptr, deg, csr_src,
                                                  as2, ad2, b2, out);
}